// Round 1
// 457.084 us; speedup vs baseline: 1.0179x; 1.0179x over previous
//
#include <hip/hip_runtime.h>
#include <math.h>

#define BETA 0.9f
#define THR  1.0f
#define LEAK 0.9f
#define BB   32
#define DIN  1024
#define DOUT 1024

// d_out flat layout (return order): s, E_W2, E_b2, Rh_W2, Rh_b2, g_bar2, r2
#define OFF_S    0
#define OFF_EW   (BB*DOUT)                         // 32768
#define OFF_EB   (OFF_EW + BB*DIN*DOUT)            // 33587200
#define OFF_RHW  (OFF_EB + BB*DOUT)                // 33619968
#define OFF_RHB  (OFF_RHW + BB*DIN*DOUT)           // 67174400
#define OFF_GBAR (OFF_RHB + BB*DOUT)               // 67207168
#define OFF_R2   (OFF_GBAR + BB*DOUT)              // 67239936

typedef float v4f __attribute__((ext_vector_type(4)));

// Kernel 1: h = x@W + b, then all per-(b,o) pointwise outputs.
// grid = (DOUT/256, B) = (4, 32), block = 256 (4 waves; each wave owns a
// K-quarter and all 256 output columns as float4 per lane).
// W load per wave-instruction: 64 lanes x 16 B = 1 KB contiguous (was 256 B).
__global__ __launch_bounds__(256) void k1_matmul_pointwise(
    const float* __restrict__ x, const float* __restrict__ W,
    const float* __restrict__ bias, const float* __restrict__ u,
    const float* __restrict__ E_b, const float* __restrict__ Rh_b,
    const float* __restrict__ g_bar, const float* __restrict__ r,
    float* __restrict__ out)
{
    const int batch = blockIdx.y;
    const int obase = blockIdx.x * 256;
    const int t    = threadIdx.x;
    const int lane = t & 63;      // column group within the 256-wide strip
    const int kc   = t >> 6;      // wave id = K-quarter 0..3

    const float* xrow = x + batch * DIN;
    const int k0 = kc * (DIN / 4);
    const float* wp = W + (size_t)k0 * DOUT + obase + lane * 4;

    v4f acc = 0.f;
    #pragma unroll 8
    for (int j = 0; j < DIN / 4; ++j) {
        const float xk = xrow[k0 + j];
        const v4f  w4 = *(const v4f*)wp;
        acc.x = fmaf(xk, w4.x, acc.x);
        acc.y = fmaf(xk, w4.y, acc.y);
        acc.z = fmaf(xk, w4.z, acc.z);
        acc.w = fmaf(xk, w4.w, acc.w);
        wp += DOUT;
    }

    __shared__ v4f red[4][64];
    red[kc][lane] = acc;
    __syncthreads();

    if (t < 64) {
        const v4f a = red[0][lane], b4 = red[1][lane],
                  c4 = red[2][lane], d4 = red[3][lane];
        const int idx  = batch * DOUT + obase + lane * 4;   // 16B-aligned
        const int oidx = obase + lane * 4;

        const v4f bb = *(const v4f*)(bias + oidx);
        const v4f uu = *(const v4f*)(u     + idx);
        const v4f eb = *(const v4f*)(E_b   + idx);
        const v4f rh = *(const v4f*)(Rh_b  + idx);
        const v4f gb = *(const v4f*)(g_bar + idx);

        const float rb    = r[batch];
        const float r2    = fmaf(LEAK, rb, 1.f);
        const float ratio = (LEAK * rb) / r2;

        v4f h4;
        h4.x = a.x + b4.x + c4.x + d4.x + bb.x;
        h4.y = a.y + b4.y + c4.y + d4.y + bb.y;
        h4.z = a.z + b4.z + c4.z + d4.z + bb.z;
        h4.w = a.w + b4.w + c4.w + d4.w + bb.w;

        v4f s4, eb2, rhb2, gb2;
        #pragma unroll
        for (int c = 0; c < 4; ++c) {
            const float un   = fmaf(BETA, uu[c], h4[c]);
            const float s    = 1.f / (1.f + expf(-(un - THR)));
            const float sg   = s * (1.f - s);
            const float dsdu = BETA * sg;

            const float eb1  = fmaf(BETA, eb[c], 1.f);
            const float dthb = fmaf(dsdu, eb1, sg);

            s4[c]   = s;
            eb2[c]  = fmaf(BETA, eb1, 1.f);
            rhb2[c] = fmaf(dsdu, rh[c], dthb);
            gb2[c]  = fmaf(ratio, gb[c], (1.f - ratio) * dsdu);
        }

        *(v4f*)(out + OFF_S    + idx) = s4;
        *(v4f*)(out + OFF_EB   + idx) = eb2;
        *(v4f*)(out + OFF_RHB  + idx) = rhb2;
        *(v4f*)(out + OFF_GBAR + idx) = gb2;
        if (blockIdx.x == 0 && t == 0) out[OFF_R2 + batch] = r2;
    }
}

// Kernel 2: the 32M-element trace update over (B, DIN, DOUT).
// grid = B*DIN blocks (one per (b,i) row), block = 256 threads, float4/thread.
// The four 128 MB streams are touch-once -> nontemporal hints keep L2/L3
// clean for the shared s-rows / x / W.
__global__ __launch_bounds__(256) void k2_traces(
    const float* __restrict__ x, const float* __restrict__ E_W,
    const float* __restrict__ Rh_W, float* __restrict__ out)
{
    const long long row   = blockIdx.x;       // b*DIN + i
    const int       batch = (int)(row >> 10); // / DIN
    const int       t     = threadIdx.x;

    const float xv = x[row];                  // broadcast scalar per block

    // s row is reused by 1024 blocks per batch -> keep cached (no nt)
    const v4f s4 = ((const v4f*)(out + OFF_S + (long long)batch * DOUT))[t];

    const long long roff = row * DOUT;
    const v4f ew = __builtin_nontemporal_load((const v4f*)(E_W  + roff) + t);
    const v4f rh = __builtin_nontemporal_load((const v4f*)(Rh_W + roff) + t);

    v4f ew2, rh2;
    #pragma unroll
    for (int c = 0; c < 4; ++c) {
        const float sg   = s4[c] * (1.f - s4[c]);
        const float dsdu = BETA * sg;
        const float e1   = fmaf(BETA, ew[c], xv);
        const float dth  = fmaf(dsdu, e1, xv * sg);
        ew2[c] = fmaf(BETA, e1, xv);
        rh2[c] = fmaf(dsdu, rh[c], dth);
    }

    __builtin_nontemporal_store(ew2, (v4f*)(out + OFF_EW  + roff) + t);
    __builtin_nontemporal_store(rh2, (v4f*)(out + OFF_RHW + roff) + t);
}

extern "C" void kernel_launch(void* const* d_in, const int* in_sizes, int n_in,
                              void* d_out, int out_size, void* d_ws, size_t ws_size,
                              hipStream_t stream) {
    const float* x     = (const float*)d_in[0];
    const float* W     = (const float*)d_in[1];
    const float* bias  = (const float*)d_in[2];
    const float* u     = (const float*)d_in[3];
    const float* E_W   = (const float*)d_in[4];
    const float* E_b   = (const float*)d_in[5];
    const float* Rh_W  = (const float*)d_in[6];
    const float* Rh_b  = (const float*)d_in[7];
    const float* g_bar = (const float*)d_in[8];
    const float* r     = (const float*)d_in[9];
    float* out = (float*)d_out;

    dim3 g1(DOUT / 256, BB);
    k1_matmul_pointwise<<<g1, 256, 0, stream>>>(x, W, bias, u, E_b, Rh_b, g_bar, r, out);
    k2_traces<<<BB * DIN, 256, 0, stream>>>(x, E_W, Rh_W, out);
}